// Round 7
// baseline (530.491 us; speedup 1.0000x reference)
//
#include <hip/hip_runtime.h>
#include <hip/hip_bf16.h>
#include <hip/hip_fp16.h>
#include <math.h>

// Encoder_DRNN via fp16 MFMA, v2: structural weight residency.
//  - U (Whh) in LDS, fragment-linear -> conflict-free ds_read_b128.
//  - W (Wih) streamed per 4-step burst; gi kept in 48 MFMA-accum VGPRs.
//  - Activations stored fragment-linear (16-row panels of 2KB): x loads are
//    contiguous-1KB-per-instr, h-state LDS reads conflict-free.
// Batch sort/unsort in the reference is a mathematical no-op -> skipped.
// Dilation: time-major row space; each dilated step is a 16-aligned panel.
//
// Fragment maps (validated by round-3 PASS):
//   A (MxK): lane holds A[lane&15][kc*32 + (lane>>4)*8 + j]
//   B = W[col][k]: lane holds W[g*128 + w*16 + (lane&15)][same k]
//   C/D: col = lane&15 (-> c = w*16+l15), row = (lane>>4)*4 + j
// Frag-linear storage: element (fragid, lane, j) at ((fragid*64+lane)*8+j).
//   Weights: fragid = w*12 + gate*4 + kc.
//   Activations: panel p (16 rows), fragid = p*4 + kc.

#define B_N 4096
#define T_N 50
#define H_N 128

typedef _Float16 half8 __attribute__((ext_vector_type(8)));
typedef float f32x4 __attribute__((ext_vector_type(4)));

#define MFMA16(a, b, c) __builtin_amdgcn_mfma_f32_16x16x32_f16((a), (b), (c), 0, 0, 0)

// ---- weight prep: fp32 [384][128] -> fp16 frag-linear; bias combine ----
__global__ void prep_weights_kernel(const float* __restrict__ Wih,
                                    const float* __restrict__ Whh,
                                    const float* __restrict__ bih,
                                    const float* __restrict__ bhh,
                                    _Float16* __restrict__ WihF,
                                    _Float16* __restrict__ WhhF,
                                    float* __restrict__ biasP) {
  const int g = blockIdx.x;      // 0..383 = gate*128 + c
  const int k = threadIdx.x;     // 0..127
  const int gate = g >> 7, c = g & 127;
  const int wv = c >> 4, kc = k >> 5;
  const int lane = (c & 15) | (((k >> 3) & 3) << 4);
  const int idx = ((wv * 12 + gate * 4 + kc) * 64 + lane) * 8 + (k & 7);
  WihF[idx] = (_Float16)Wih[(size_t)g * H_N + k];
  WhhF[idx] = (_Float16)Whh[(size_t)g * H_N + k];
  if (k == 0) {
    if (g < 256) biasP[g] = bih[g] + bhh[g];             // r,z: fold sums
    else { biasP[g] = bih[g]; biasP[g + 128] = bhh[g]; } // n: keep split
  }
}

// ---- embedding gather -> frag-linear fp16 panels ----
__global__ void gather_kernel(const int* __restrict__ tok,
                              const float* __restrict__ emb,
                              _Float16* __restrict__ XF) {
  const int p    = blockIdx.x;            // panel 0..12799
  const int tid  = threadIdx.x;           // 256
  const int kc   = tid >> 6;
  const int lane = tid & 63;
  const int row  = p * 16 + (lane & 15);  // time-major row
  const int t    = row >> 12;
  const int b    = row & (B_N - 1);
  const int c8   = kc * 32 + (lane >> 4) * 8;
  const int tk   = tok[b * T_N + t];
  const float4* ep = (const float4*)(emb + (size_t)tk * H_N + c8);
  const float4 a = ep[0], d = ep[1];
  half8 v = { (_Float16)a.x, (_Float16)a.y, (_Float16)a.z, (_Float16)a.w,
              (_Float16)d.x, (_Float16)d.y, (_Float16)d.z, (_Float16)d.w };
  *(half8*)(XF + (((size_t)p * 4 + kc) * 64 + lane) * 8) = v;
}

// ---- sentence mask ----
__global__ void mask_kernel(const int* __restrict__ tok, float* __restrict__ mask) {
  const int b = blockIdx.x * 256 + threadIdx.x;
  int any = 0;
  for (int t = 0; t < T_N; ++t) any |= tok[b * T_N + t];
  mask[b] = any ? 1.0f : 0.0f;
}

__device__ __forceinline__ float sigm(float x) {
  return 1.0f / (1.0f + __expf(-x));
}
__device__ __forceinline__ float tanh_fast(float x) {
  x = fminf(fmaxf(x, -15.0f), 15.0f);
  const float t = __expf(2.0f * x);
  return (t - 1.0f) / (t + 1.0f);
}

// ---- fused GRU layer: U in LDS, W burst-streamed, gi in accum VGPRs ----
template <int RATE, int TSTEPS, bool LAST>
__global__ __launch_bounds__(512, 2) void gru_mfma_kernel(
    const _Float16* __restrict__ XF, void* __restrict__ Yv,
    const _Float16* __restrict__ WihF, const _Float16* __restrict__ WhhF,
    const float* __restrict__ biasP, const float* __restrict__ maskF) {
  extern __shared__ _Float16 lds[];       // U: [0,49152)  hs: [49152,53248)
  _Float16* Ul  = lds;
  _Float16* hsl = lds + 49152;            // 2 bufs x 2048 halves

  const int tid  = threadIdx.x;
  const int lane = tid & 63;
  const int w    = tid >> 6;              // wave 0..7
  const int l15  = lane & 15;
  const int lq   = lane >> 4;
  const int c    = (w << 4) + l15;        // this lane's output column
  const int d0   = blockIdx.x << 4;       // dilated-row base (panel-aligned)

  // stage U into LDS (frag-linear copy: coalesced + conflict-free)
  for (int i = tid; i < 6144; i += 512)
    *(half8*)(Ul + i * 8) = *(const half8*)(WhhF + (size_t)i * 8);
  // zero h state (both buffers)
  for (int i = tid; i < 512; i += 512)
    *(half8*)(hsl + i * 8) = half8{0,0,0,0,0,0,0,0};

  const float br = biasP[c],       bz = biasP[128 + c];
  const float bi = biasP[256 + c], bh = biasP[384 + c];
  float mkv[4];
#pragma unroll
  for (int j = 0; j < 4; ++j)
    mkv[j] = LAST ? maskF[(d0 & (B_N - 1)) + lq * 4 + j] : 0.0f;

  float hold[4] = {0.f, 0.f, 0.f, 0.f};
  __syncthreads();

  int cur = 0;
  for (int tp0 = 0; tp0 < TSTEPS; tp0 += 4) {
    const int bs = (TSTEPS - tp0 < 4) ? (TSTEPS - tp0) : 4;

    // ---- burst x-GEMM: gi for up to 4 steps, held in accum VGPRs ----
    f32x4 gr[4], gz[4], gn[4];
#pragma unroll
    for (int s = 0; s < 4; ++s) {
      gr[s] = f32x4{br, br, br, br};
      gz[s] = f32x4{bz, bz, bz, bz};
      gn[s] = f32x4{bi, bi, bi, bi};
    }
#pragma unroll
    for (int kc = 0; kc < 4; ++kc) {
      const int wf = (w * 12 + kc) * 64 + lane;
      const half8 wr = *(const half8*)(WihF + (size_t)(wf      ) * 8);
      const half8 wz = *(const half8*)(WihF + (size_t)(wf + 256) * 8);
      const half8 wn = *(const half8*)(WihF + (size_t)(wf + 512) * 8);
#pragma unroll
      for (int s = 0; s < 4; ++s) {
        if (s < bs) {
          const size_t panel = (size_t)(tp0 + s) * RATE * 256 + blockIdx.x;
          const half8 xv =
              *(const half8*)(XF + ((panel * 4 + kc) * 64 + lane) * 8);
          gr[s] = MFMA16(xv, wr, gr[s]);
          gz[s] = MFMA16(xv, wz, gz[s]);
          gn[s] = MFMA16(xv, wn, gn[s]);
        }
      }
    }

    // ---- sequential h sub-steps ----
#pragma unroll
    for (int s = 0; s < 4; ++s) {
      if (s < bs) {
        const int tp = tp0 + s;
        half8 hf[4];
#pragma unroll
        for (int kc = 0; kc < 4; ++kc)
          hf[kc] = *(const half8*)(hsl + cur * 2048 + (kc * 64 + lane) * 8);

        f32x4 ar = gr[s], az = gz[s], an = gn[s];
        f32x4 ah = f32x4{bh, bh, bh, bh};
#pragma unroll
        for (int kc = 0; kc < 4; ++kc) {
          const int uf = (w * 12 + kc) * 64 + lane;
          const half8 ur = *(const half8*)(Ul + (uf      ) * 8);
          const half8 uz = *(const half8*)(Ul + (uf + 256) * 8);
          const half8 un = *(const half8*)(Ul + (uf + 512) * 8);
          ar = MFMA16(hf[kc], ur, ar);
          az = MFMA16(hf[kc], uz, az);
          ah = MFMA16(hf[kc], un, ah);
        }

        const int nxt = cur ^ 1;
#pragma unroll
        for (int j = 0; j < 4; ++j) {
          const int crow = lq * 4 + j;
          const float rr = sigm(ar[j]);
          const float zz = sigm(az[j]);
          const float nn = tanh_fast(an[j] + rr * ah[j]);
          const float hv = nn + zz * (hold[j] - nn);
          hold[j] = hv;
          const _Float16 hh = (_Float16)hv;
          // frag-linear index for (row=crow, col=c)
          const int hidx = ((c >> 5) * 64 + crow + ((c >> 3) & 3) * 16) * 8
                           + (c & 7);
          hsl[nxt * 2048 + hidx] = hh;
          if (!LAST) {
            const size_t panel = (size_t)tp * RATE * 256 + blockIdx.x;
            ((_Float16*)Yv)[panel * 2048 + hidx] = hh;
          } else {
            const int d = d0 + crow;
            const int t = tp * RATE + (d >> 12);
            if (t < T_N) {
              const int b = d & (B_N - 1);
              ((float*)Yv)[((size_t)b * T_N + t) * H_N + c] = hv * mkv[j];
            }
          }
        }
        cur ^= 1;
        __syncthreads();
      }
    }
  }
}

// ---- launcher ----
#define LDS_BYTES 106496

extern "C" void kernel_launch(void* const* d_in, const int* in_sizes, int n_in,
                              void* d_out, int out_size, void* d_ws, size_t ws_size,
                              hipStream_t stream) {
  (void)in_sizes; (void)n_in; (void)out_size; (void)ws_size;
  const int*   tok = (const int*)d_in[0];
  const float* emb = (const float*)d_in[3];

  char* ws = (char*)d_ws;
  const size_t XBYTES = (size_t)212992 * H_N * 2;   // 54,525,952
  _Float16* X0   = (_Float16*)ws;
  _Float16* X1   = (_Float16*)(ws + XBYTES);
  _Float16* WihF = (_Float16*)(ws + 2 * XBYTES);            // 3 x 49152 halves
  _Float16* WhhF = WihF + 3 * 49152;
  float*    biasP = (float*)(WhhF + 3 * 49152);
  float*    maskF = biasP + 3 * 512;

  for (int l = 0; l < 3; ++l) {
    prep_weights_kernel<<<384, 128, 0, stream>>>(
        (const float*)d_in[4 + 4 * l], (const float*)d_in[5 + 4 * l],
        (const float*)d_in[6 + 4 * l], (const float*)d_in[7 + 4 * l],
        WihF + (size_t)l * 49152, WhhF + (size_t)l * 49152, biasP + l * 512);
  }
  gather_kernel<<<12800, 256, 0, stream>>>(tok, emb, X0);
  mask_kernel<<<16, 256, 0, stream>>>(tok, maskF);
  // zero pad panels (rows 204800..212991) of X0 for layer-2's t=50,51
  hipMemsetAsync(X0 + (size_t)204800 * H_N, 0,
                 (size_t)(212992 - 204800) * H_N * 2, stream);

  hipFuncSetAttribute((const void*)&gru_mfma_kernel<1, 50, false>,
                      hipFuncAttributeMaxDynamicSharedMemorySize, LDS_BYTES);
  hipFuncSetAttribute((const void*)&gru_mfma_kernel<2, 25, false>,
                      hipFuncAttributeMaxDynamicSharedMemorySize, LDS_BYTES);
  hipFuncSetAttribute((const void*)&gru_mfma_kernel<4, 13, true>,
                      hipFuncAttributeMaxDynamicSharedMemorySize, LDS_BYTES);

  // layer 0: rate 1, 50 steps, 256 panels : X0 -> X1
  gru_mfma_kernel<1, 50, false><<<256, 512, LDS_BYTES, stream>>>(
      X0, X1, WihF, WhhF, biasP, maskF);
  // layer 1: rate 2, 25 steps, 512 panels : X1 -> X0
  gru_mfma_kernel<2, 25, false><<<512, 512, LDS_BYTES, stream>>>(
      X1, X0, WihF + 49152, WhhF + 49152, biasP + 512, maskF);
  // layer 2: rate 4, 13 steps, 1024 panels: X0 -> d_out (fp32, masked)
  gru_mfma_kernel<4, 13, true><<<1024, 512, LDS_BYTES, stream>>>(
      X0, (float*)d_out, WihF + 2 * 49152, WhhF + 2 * 49152,
      biasP + 1024, maskF);
}